// Round 1
// baseline (122.364 us; speedup 1.0000x reference)
//
#include <hip/hip_runtime.h>

// Problem constants
#define NN 16      // batch
#define PB 16      // predicted masks
#define TB 8       // true masks
#define HWPX 50176 // 224*224
#define WORDS 784  // u64 words per plane (50176/64)
#define GROUPS 196 // 256-pixel groups per plane (50176/256)

// ---------------------------------------------------------------------------
// K0: zero the small accumulators (ws is poisoned 0xAA before every call)
// ---------------------------------------------------------------------------
__global__ void zero_kernel(float* __restrict__ inters, float* __restrict__ sp,
                            float* __restrict__ st, float* __restrict__ out) {
    int i = threadIdx.x + blockIdx.x * blockDim.x;   // grid covers 2048
    if (i < NN * PB * TB) inters[i] = 0.f;
    if (i < NN * PB) sp[i] = 0.f;
    if (i < NN * TB) st[i] = 0.f;
    if (i < NN) out[i] = 0.f;
}

// ---------------------------------------------------------------------------
// K1: bitpack both inputs. Each wave-iteration: 64 lanes load float4 (1 KiB
// coalesced), 4 ballots -> 4 u64 words. Pixel->bit mapping is a fixed
// permutation, identical for pred and true planes, so popcount-intersections
// and the (permutation-invariant) final mean are unaffected.
// ---------------------------------------------------------------------------
__global__ void pack_kernel(const float* __restrict__ pred,
                            const float* __restrict__ truth,
                            unsigned long long* __restrict__ PP,
                            unsigned long long* __restrict__ PT) {
    const int totalGroups = (NN * PB + NN * TB) * GROUPS;  // 75264
    const int wavesPerBlock = blockDim.x >> 6;
    const int waveId = blockIdx.x * wavesPerBlock + (threadIdx.x >> 6);
    const int lane = threadIdx.x & 63;
    const int nWaves = gridDim.x * wavesPerBlock;

    for (int G = waveId; G < totalGroups; G += nWaves) {
        int plane = G / GROUPS;
        int g = G - plane * GROUPS;
        const float* src;
        unsigned long long* dst;
        if (plane < NN * PB) {
            src = pred + (size_t)plane * HWPX;
            dst = PP + (size_t)plane * WORDS;
        } else {
            int q = plane - NN * PB;
            src = truth + (size_t)q * HWPX;
            dst = PT + (size_t)q * WORDS;
        }
        const float4 v = *(const float4*)(src + g * 256 + lane * 4);
        unsigned long long b0 = __ballot(v.x != 0.0f);
        unsigned long long b1 = __ballot(v.y != 0.0f);
        unsigned long long b2 = __ballot(v.z != 0.0f);
        unsigned long long b3 = __ballot(v.w != 0.0f);
        if (lane == 0) {
            dst[g * 4 + 0] = b0;
            dst[g * 4 + 1] = b1;
            dst[g * 4 + 2] = b2;
            dst[g * 4 + 3] = b3;
        }
    }
}

// ---------------------------------------------------------------------------
// K2: inters[n,p,t] = popcount(PP[n,p] & PT[n,t]); also sp, st.
// grid = NN * SPLIT blocks, 128 threads = one (p,t) pair each,
// each block handles 28 words (784 = 28 * SPLIT with SPLIT = 28).
// ---------------------------------------------------------------------------
#define K2_SPLIT 28
__global__ void inters_kernel(const unsigned long long* __restrict__ PP,
                              const unsigned long long* __restrict__ PT,
                              float* __restrict__ inters,
                              float* __restrict__ sp, float* __restrict__ st) {
    const int n = blockIdx.x / K2_SPLIT;
    const int s = blockIdx.x % K2_SPLIT;
    const int p = threadIdx.x >> 3;
    const int t = threadIdx.x & 7;
    const unsigned long long* pp = PP + ((size_t)n * PB + p) * WORDS;
    const unsigned long long* pt = PT + ((size_t)n * TB + t) * WORDS;
    const int w0 = s * (WORDS / K2_SPLIT);
    int acc = 0, accp = 0, acct = 0;
#pragma unroll 4
    for (int w = w0; w < w0 + (WORDS / K2_SPLIT); ++w) {
        unsigned long long a = pp[w];
        unsigned long long b = pt[w];
        acc += __popcll(a & b);
        accp += __popcll(a);
        acct += __popcll(b);
    }
    atomicAdd(&inters[((size_t)n * PB + p) * TB + t], (float)acc);
    if (t == 0) atomicAdd(&sp[n * PB + p], (float)accp);
    if (p == 0) atomicAdd(&st[n * TB + t], (float)acct);
}

// ---------------------------------------------------------------------------
// K3: per-block recompute iou_maxs[n,:] (cheap), then per-pixel score from
// packed pred bits, block-reduce, one atomicAdd per block.
// grid = NN * CH blocks (CH=16), 256 threads; 49 words per block.
// ---------------------------------------------------------------------------
#define K3_CH 16
__global__ void score_kernel(const unsigned long long* __restrict__ PP,
                             const float* __restrict__ inters,
                             const float* __restrict__ sp,
                             const float* __restrict__ st,
                             float* __restrict__ out) {
    const int n = blockIdx.x / K3_CH;
    const int c = blockIdx.x % K3_CH;
    __shared__ float ioumax_s[PB];
    __shared__ float redbuf[4];

    if (threadIdx.x < PB) {
        int p = threadIdx.x;
        float spv = sp[n * PB + p];
        float m = 0.f;
#pragma unroll
        for (int t = 0; t < TB; ++t) {
            float iv = inters[((size_t)n * PB + p) * TB + t];
            float un = spv + st[n * TB + t] - iv;
            float iou = un > 0.f ? iv / un : 0.f;
            m = fmaxf(m, iou);
        }
        ioumax_s[p] = m;
    }
    __syncthreads();

    const int lane = threadIdx.x & 63;
    const int wv = threadIdx.x >> 6;
    const int wpb = WORDS / K3_CH;  // 49
    float sum = 0.f;
    for (int w = c * wpb + wv; w < (c + 1) * wpb; w += 4) {
        float num = 0.f, den = 0.f;
#pragma unroll
        for (int p = 0; p < PB; ++p) {
            unsigned long long m = PP[((size_t)n * PB + p) * WORDS + w];
            float b = (float)((m >> lane) & 1ull);
            den += b;
            num += b * ioumax_s[p];
        }
        sum += den > 0.f ? num / den : 0.f;
    }
    // wave reduce
#pragma unroll
    for (int off = 32; off > 0; off >>= 1) sum += __shfl_down(sum, off, 64);
    if (lane == 0) redbuf[wv] = sum;
    __syncthreads();
    if (threadIdx.x == 0) {
        float tot = redbuf[0] + redbuf[1] + redbuf[2] + redbuf[3];
        atomicAdd(&out[n], tot * (1.0f / (float)HWPX));
    }
}

// ---------------------------------------------------------------------------
extern "C" void kernel_launch(void* const* d_in, const int* in_sizes, int n_in,
                              void* d_out, int out_size, void* d_ws, size_t ws_size,
                              hipStream_t stream) {
    const float* pred = (const float*)d_in[0];   // (N,P,H,W) fp32 {0,1}
    const float* truth = (const float*)d_in[1];  // (N,T,H,W) fp32 {0,1}
    float* out = (float*)d_out;                  // (N,)

    // workspace layout
    unsigned long long* PP = (unsigned long long*)d_ws;          // 200704 u64
    unsigned long long* PT = PP + (size_t)NN * PB * WORDS;       // 100352 u64
    float* inters = (float*)(PT + (size_t)NN * TB * WORDS);      // 2048 f32
    float* sp = inters + NN * PB * TB;                           // 256 f32
    float* st = sp + NN * PB;                                    // 128 f32

    zero_kernel<<<2, 1024, 0, stream>>>(inters, sp, st, out);
    pack_kernel<<<1024, 256, 0, stream>>>(pred, truth, PP, PT);
    inters_kernel<<<NN * K2_SPLIT, 128, 0, stream>>>(PP, PT, inters, sp, st);
    score_kernel<<<NN * K3_CH, 256, 0, stream>>>(PP, inters, sp, st, out);
}